// Round 8
// baseline (174.086 us; speedup 1.0000x reference)
//
#include <hip/hip_runtime.h>
#include <hip/hip_bf16.h>

#define Bsz 64
#define Wln 512
#define Hd  1024
#define Vc  32000

typedef short v8s __attribute__((ext_vector_type(8)));
typedef float f32x4 __attribute__((ext_vector_type(4)));

__device__ inline unsigned short f2b(float f) {  // round to bf16
  union { float f; unsigned u; } v; v.f = f;
  return (unsigned short)((v.u + 0x8000u) >> 16);
}
__device__ inline float wave_sum(float v) {
  #pragma unroll
  for (int o = 32; o; o >>= 1) v += __shfl_down(v, o);
  return v;
}
__device__ inline float wave_max(float v) {
  #pragma unroll
  for (int o = 32; o; o >>= 1) v = fmaxf(v, __shfl_down(v, o));
  return v;
}
__device__ inline float sigm(float x) { return 1.f / (1.f + expf(-x)); }

__device__ inline v8s cvt_frag(float4 x0, float4 x1) {
  v8s r;
  r[0] = (short)f2b(x0.x); r[1] = (short)f2b(x0.y);
  r[2] = (short)f2b(x0.z); r[3] = (short)f2b(x0.w);
  r[4] = (short)f2b(x1.x); r[5] = (short)f2b(x1.y);
  r[6] = (short)f2b(x1.z); r[7] = (short)f2b(x1.w);
  return r;
}

// ---- fused: attention scores (blocks 0..8191) + s_att/emb gather (blocks 8192..8255) ----
__global__ __launch_bounds__(256) void k_scores_satt(
    const float* __restrict__ enc, const float* __restrict__ att_w,
    const float* __restrict__ h0, const float* __restrict__ c0,
    const float* __restrict__ att_b, const int* __restrict__ input,
    const float* __restrict__ emb,
    float* __restrict__ scores, float* __restrict__ s_att,
    float* __restrict__ embbuf)
{
  __shared__ float red[4];
  int t = threadIdx.x;
  if (blockIdx.x < 8192) {
    int row = blockIdx.x * 4 + (t >> 6);
    int lane = t & 63;
    const float* p = enc + (size_t)row * Hd + lane * 16;
    const float* w = att_w + lane * 16;
    float s = 0.f;
    #pragma unroll
    for (int c = 0; c < 4; ++c) {
      float4 e = *(const float4*)(p + c * 4);
      float4 ww = *(const float4*)(w + c * 4);
      s += e.x * ww.x + e.y * ww.y + e.z * ww.z + e.w * ww.w;
    }
    s = wave_sum(s);
    if (lane == 0) scores[row] = s;     // s_att added later (softmax)
  } else {
    int b = blockIdx.x - 8192;
    int idx = input[b];
    for (int j = t; j < Hd; j += 256)
      embbuf[b * Hd + j] = emb[(size_t)idx * Hd + j];
    size_t base = (size_t)(Bsz + b) * Hd;  // layer L-1 = 1
    float s = 0.f;
    for (int j = t; j < Hd; j += 256)
      s += h0[base + j] * c0[base + j] * att_w[Hd + j];
    s = wave_sum(s);
    if ((t & 63) == 0) red[t >> 6] = s;
    __syncthreads();
    if (t == 0) s_att[b] = red[0] + red[1] + red[2] + red[3] + att_b[0];
  }
}

// ---- ctx partials with in-block softmax: block = (b, chunk of 64 w-rows) ----
__global__ __launch_bounds__(256) void k_ctx_part(
    const float* __restrict__ scores, const float* __restrict__ s_att,
    const float* __restrict__ enc, float* __restrict__ part)  // part[b][8][Hd]
{
  int b = blockIdx.x >> 3, ch = blockIdx.x & 7;
  int t = threadIdx.x;
  float sa = s_att[b];
  const float* sr = scores + b * Wln;
  // shifted softmax over 512 positions: full[0]=0, full[w]=sr[w-1]+sa
  int w0 = t * 2, w1 = t * 2 + 1;
  float v0 = (w0 == 0) ? 0.f : sr[w0 - 1] + sa;
  float v1 = sr[w1 - 1] + sa;
  __shared__ float redm[4], reds[4];
  float m = fmaxf(v0, v1);
  m = wave_max(m);
  if ((t & 63) == 0) redm[t >> 6] = m;
  __syncthreads();
  float M = fmaxf(fmaxf(redm[0], redm[1]), fmaxf(redm[2], redm[3]));
  float e = expf(v0 - M) + expf(v1 - M);
  e = wave_sum(e);
  if ((t & 63) == 0) reds[t >> 6] = e;
  __syncthreads();
  float S = reds[0] + reds[1] + reds[2] + reds[3];
  __shared__ float w[64];
  if (t < 64) {
    int wg = ch * 64 + t;
    float v = (wg == 0) ? 0.f : sr[wg - 1] + sa;
    w[t] = expf(v - M) / S;
  }
  __syncthreads();
  int h4 = t * 4;
  const float* p = enc + (size_t)b * Wln * Hd + (size_t)ch * 64 * Hd + h4;
  float a0 = 0, a1 = 0, a2 = 0, a3 = 0;
  #pragma unroll 4
  for (int i = 0; i < 64; ++i) {
    float4 ev = *(const float4*)(p + (size_t)i * Hd);
    float wi = w[i];
    a0 += wi * ev.x; a1 += wi * ev.y; a2 += wi * ev.z; a3 += wi * ev.w;
  }
  float* o = part + ((size_t)b * 8 + ch) * Hd + h4;
  o[0] = a0; o[1] = a1; o[2] = a2; o[3] = a3;
}

// ---- GEMM v5: C(64 x N) = A(64 x 1024) * B(N x 1024)^T + bias ----
// A staged once per block in LDS (bf16, XOR-swizzled). 8 waves; NS n-subtiles
// of 16 cols; KS=8/NS K-split with LDS-reuse reduction. Dual problem sets by
// blockIdx. p81: set-1 A is the sum of 8 partials (stride Hd, row stride sA1).
template<int NS>
__global__ __launch_bounds__(512) void gemm_v5(
    const float* __restrict__ A1, const float* __restrict__ A1b, int sA1,
    const float* __restrict__ B1, int sB1, const float* __restrict__ bias1,
    float* __restrict__ out1,
    const float* __restrict__ A2, const float* __restrict__ A2b, int sA2,
    const float* __restrict__ B2, int sB2, const float* __restrict__ bias2,
    float* __restrict__ out2,
    int N, int nblk1, int p81)
{
  constexpr int KS  = 8 / NS;       // K-split ways
  constexpr int KSL = 1024 / KS;    // k-slice per wave
  const int tid = threadIdx.x;

  const float *A, *Ab, *B, *bias; float* out; int sA, sB, bid, p8;
  if ((int)blockIdx.x < nblk1) {
    A = A1; Ab = A1b; sA = sA1; B = B1; sB = sB1; bias = bias1; out = out1;
    bid = blockIdx.x; p8 = p81;
  } else {
    A = A2; Ab = A2b; sA = sA2; B = B2; sB = sB2; bias = bias2; out = out2;
    bid = blockIdx.x - nblk1; p8 = 0;
  }

  __shared__ __align__(16) char pool[131072];   // 64 x 1024 bf16, swizzled

  // ---- stage A -> LDS bf16 ----
  #pragma unroll
  for (int it = 0; it < 16; ++it) {
    int idx = it * 512 + tid;
    int row = idx >> 7, ch = idx & 127;       // 128 chunks of 8 f32 per row
    float4 x0, x1;
    if (p8) {
      const float* src = A + (size_t)row * sA + ch * 8;
      x0.x = x0.y = x0.z = x0.w = 0.f; x1 = x0;
      #pragma unroll
      for (int c = 0; c < 8; ++c) {
        float4 y0 = *(const float4*)(src + c * Hd);
        float4 y1 = *(const float4*)(src + c * Hd + 4);
        x0.x += y0.x; x0.y += y0.y; x0.z += y0.z; x0.w += y0.w;
        x1.x += y1.x; x1.y += y1.y; x1.z += y1.z; x1.w += y1.w;
      }
    } else {
      const float* src = A + (size_t)row * sA + ch * 8;
      x0 = *(const float4*)src;
      x1 = *(const float4*)(src + 4);
      if (Ab) {
        const float* s2 = Ab + (size_t)row * sA + ch * 8;
        float4 y0 = *(const float4*)s2;
        float4 y1 = *(const float4*)(s2 + 4);
        x0.x += y0.x; x0.y += y0.y; x0.z += y0.z; x0.w += y0.w;
        x1.x += y1.x; x1.y += y1.y; x1.z += y1.z; x1.w += y1.w;
      }
    }
    *(v8s*)(pool + row * 2048 + ((ch * 16) ^ ((row & 7) << 4))) = cvt_frag(x0, x1);
  }
  __syncthreads();

  const int w = tid >> 6, lane = tid & 63;
  const int r = lane & 15, q = lane >> 4;
  const int nsub = w % NS, kh = w / NS;
  const int n0 = bid * (NS * 16);

  f32x4 acc[4] = {{0,0,0,0},{0,0,0,0},{0,0,0,0},{0,0,0,0}};
  const float* bp = B + (size_t)(n0 + nsub * 16 + r) * sB + kh * KSL + q * 8;
  const int swz = (r & 7) << 4;

  #pragma unroll
  for (int kk = 0; kk < KSL / 32; ++kk) {
    float4 b0 = *(const float4*)(bp + kk * 32);
    float4 b1 = *(const float4*)(bp + kk * 32 + 4);
    v8s bf = cvt_frag(b0, b1);
    int cb = ((kh * KSL + kk * 32 + q * 8) * 2) ^ swz;   // col byte, swizzled
    #pragma unroll
    for (int m = 0; m < 4; ++m) {
      v8s af = *(const v8s*)(pool + (m * 16 + r) * 2048 + cb);
      acc[m] = __builtin_amdgcn_mfma_f32_16x16x32_bf16(af, bf, acc[m], 0, 0, 0);
    }
  }

  __syncthreads();   // all A-reads done; reuse pool as reduction buffer
  float (*red)[64][17] = (float(*)[64][17])pool;
  #pragma unroll
  for (int m = 0; m < 4; ++m)
    #pragma unroll
    for (int rr = 0; rr < 4; ++rr)
      red[w][lane][m * 4 + rr] = acc[m][rr];
  __syncthreads();

  constexpr int COLS = NS * 16;
  #pragma unroll
  for (int it = 0; it < NS * 2; ++it) {
    int e = it * 512 + tid;                  // e in [0, 64*COLS)
    int cc = e % COLS, rowi = e / COLS;
    int ns2 = cc >> 4, lo = cc & 15;
    int idx = ((rowi >> 4) << 2) + (rowi & 3);
    int le  = (((rowi >> 2) & 3) << 4) + lo;
    float s = 0.f;
    #pragma unroll
    for (int j = 0; j < KS; ++j) s += red[ns2 + j * NS][le][idx];
    float bb = bias ? bias[n0 + cc] : 0.f;
    out[(size_t)rowi * N + n0 + cc] = s + bb;
  }
}

// ---- LSTM elementwise: g = g1 + g2; h,c straight to final f32 slots ----
__global__ __launch_bounds__(256) void k_lstm(
    const float* __restrict__ g1, const float* __restrict__ g2,
    const float* __restrict__ c0,
    float* __restrict__ out_h, float* __restrict__ out_c)
{
  int b = blockIdx.x >> 2;
  int j = ((blockIdx.x & 3) << 8) + threadIdx.x;
  const float* ga = g1 + (size_t)b * 4 * Hd;
  const float* gb = g2 + (size_t)b * 4 * Hd;
  float gi = ga[j] + gb[j];
  float gf = ga[Hd + j] + gb[Hd + j];
  float gg = ga[2 * Hd + j] + gb[2 * Hd + j];
  float go = ga[3 * Hd + j] + gb[3 * Hd + j];
  float c = sigm(gf) * c0[(size_t)b * Hd + j] + sigm(gi) * tanhf(gg);
  float h = sigm(go) * tanhf(c);
  out_h[b * Hd + j] = h;
  out_c[b * Hd + j] = c;
}

// ---- online (m,s) combine ----
__device__ inline void ms_comb(float& m, float& s, float mo, float so) {
  if (mo > m) { s = s * expf(m - mo) + so; m = mo; }
  else        { s += so * expf(mo - m); }
}

// ---- in-place log-softmax over V per batch row: online 2-pass ----
__global__ __launch_bounds__(1024) void k_logsoftmax(float* __restrict__ lg)
{
  int b = blockIdx.x, t = threadIdx.x;
  float* row = lg + (size_t)b * Vc;
  float m = -1e30f, s = 0.f;
  for (int w = t; w < Vc; w += 1024) {
    float v = row[w];
    if (v > m) { s = s * expf(m - v) + 1.f; m = v; }
    else       { s += expf(v - m); }
  }
  #pragma unroll
  for (int o = 32; o; o >>= 1) {
    float mo = __shfl_down(m, o), so = __shfl_down(s, o);
    ms_comb(m, s, mo, so);
  }
  __shared__ float redm[16], reds[16];
  if ((t & 63) == 0) { redm[t >> 6] = m; reds[t >> 6] = s; }
  __syncthreads();
  __shared__ float lse_sh;
  if (t == 0) {
    float M = redm[0], S = reds[0];
    #pragma unroll
    for (int i = 1; i < 16; ++i) ms_comb(M, S, redm[i], reds[i]);
    lse_sh = M + logf(S);
  }
  __syncthreads();
  float lse = lse_sh;
  for (int w = t; w < Vc; w += 1024) row[w] = row[w] - lse;
}

extern "C" void kernel_launch(void* const* d_in, const int* in_sizes, int n_in,
                              void* d_out, int out_size, void* d_ws, size_t ws_size,
                              hipStream_t stream)
{
  const int*   input = (const int*)d_in[0];
  const float* h0    = (const float*)d_in[1];
  const float* c0    = (const float*)d_in[2];
  const float* enc   = (const float*)d_in[3];
  const float* emb   = (const float*)d_in[4];
  const float* W_ih0 = (const float*)d_in[5];
  const float* W_hh0 = (const float*)d_in[6];
  const float* b_ih0 = (const float*)d_in[7];
  const float* b_hh0 = (const float*)d_in[8];
  const float* W_ih1 = (const float*)d_in[9];
  const float* W_hh1 = (const float*)d_in[10];
  const float* b_ih1 = (const float*)d_in[11];
  const float* b_hh1 = (const float*)d_in[12];
  const float* att_w = (const float*)d_in[13];
  const float* att_b = (const float*)d_in[14];
  const float* inW   = (const float*)d_in[15];
  const float* inb   = (const float*)d_in[16];
  const float* outW  = (const float*)d_in[17];
  const float* outb  = (const float*)d_in[18];
  float* out = (float*)d_out;

  // Scratch inside d_out's f32 logp region (8,192,000 B); all dead before
  // the logits GEMM overwrites it (logits reads h2/outW/outb only).
  char* sc = (char*)d_out;
  float* g1     = (float*)(sc + 0);          // 64x4096 f32 = 1 MB
  float* g2     = (float*)(sc + 1048576);    // 64x4096 f32 = 1 MB
  float* ctxp   = (float*)(sc + 2097152);    // 64x8x1024 f32 = 2 MB
  float* embbuf = (float*)(sc + 4194304);    // 64x1024 f32 = 256 KB
  float* x1     = (float*)(sc + 4718592);    // 64x1024 f32
  float* x2     = (float*)(sc + 4980736);    // 64x1024 f32
  float* scores = (float*)(sc + 5242880);    // 64x512 f32
  float* s_att  = (float*)(sc + 5505024);    // 64 f32

  float* out_h = out + (size_t)Bsz * Vc;     // [2,B,H] f32
  float* out_c = out_h + 2 * Bsz * Hd;       // [2,B,H] f32
  float* h1 = out_h;                         // layer 0 slot
  float* h2 = out_h + Bsz * Hd;              // layer 1 slot

  k_scores_satt<<<8256, 256, 0, stream>>>(enc, att_w, h0, c0, att_b, input, emb,
                                          scores, s_att, embbuf);
  k_ctx_part<<<Bsz * 8, 256, 0, stream>>>(scores, s_att, enc, ctxp);

  // input proj: x = [ctx|emb] @ inW^T + inb, K-halves -> x1 + x2
  gemm_v5<1><<<128, 512, 0, stream>>>(
      ctxp,   nullptr, 8 * Hd, inW,      2 * Hd, inb,     x1,
      embbuf, nullptr, Hd,     inW + Hd, 2 * Hd, nullptr, x2,
      Hd, 64, 1);

  // layer 0 gates: g1 = (x1+x2)@W_ih0^T + b_ih0 ; g2 = h0@W_hh0^T + b_hh0
  gemm_v5<2><<<256, 512, 0, stream>>>(
      x1, x2,      Hd, W_ih0, Hd, b_ih0, g1,
      h0, nullptr, Hd, W_hh0, Hd, b_hh0, g2,
      4 * Hd, 128, 0);
  k_lstm<<<Bsz * 4, 256, 0, stream>>>(g1, g2, c0, h1, out_c);

  // layer 1 gates
  gemm_v5<2><<<256, 512, 0, stream>>>(
      h1,                     nullptr, Hd, W_ih1, Hd, b_ih1, g1,
      h0 + (size_t)Bsz * Hd,  nullptr, Hd, W_hh1, Hd, b_hh1, g2,
      4 * Hd, 128, 0);
  k_lstm<<<Bsz * 4, 256, 0, stream>>>(g1, g2, c0 + (size_t)Bsz * Hd, h2, out_c + Bsz * Hd);

  // logits
  gemm_v5<4><<<500, 512, 0, stream>>>(
      h2,      nullptr, Hd, outW,    Hd, outb,    out,
      nullptr, nullptr, 0,  nullptr, 0,  nullptr, nullptr,
      Vc, 500, 0);
  k_logsoftmax<<<Bsz, 1024, 0, stream>>>(out);
}

// Round 9
// 149.216 us; speedup vs baseline: 1.1667x; 1.1667x over previous
//
#include <hip/hip_runtime.h>
#include <hip/hip_bf16.h>

#define Bsz 64
#define Wln 512
#define Hd  1024
#define Vc  32000

typedef short v8s __attribute__((ext_vector_type(8)));
typedef float f32x4 __attribute__((ext_vector_type(4)));

__device__ inline unsigned short f2b(float f) {  // round to bf16
  union { float f; unsigned u; } v; v.f = f;
  return (unsigned short)((v.u + 0x8000u) >> 16);
}
__device__ inline float wave_sum(float v) {
  #pragma unroll
  for (int o = 32; o; o >>= 1) v += __shfl_down(v, o);
  return v;
}
__device__ inline float wave_max(float v) {
  #pragma unroll
  for (int o = 32; o; o >>= 1) v = fmaxf(v, __shfl_down(v, o));
  return v;
}
__device__ inline float sigm(float x) { return 1.f / (1.f + expf(-x)); }

__device__ inline v8s cvt_frag(float4 x0, float4 x1) {
  v8s r;
  r[0] = (short)f2b(x0.x); r[1] = (short)f2b(x0.y);
  r[2] = (short)f2b(x0.z); r[3] = (short)f2b(x0.w);
  r[4] = (short)f2b(x1.x); r[5] = (short)f2b(x1.y);
  r[6] = (short)f2b(x1.z); r[7] = (short)f2b(x1.w);
  return r;
}

// ---- fused: attention scores (blocks 0..8191) + s_att/emb gather (blocks 8192..8255) ----
__global__ __launch_bounds__(256) void k_scores_satt(
    const float* __restrict__ enc, const float* __restrict__ att_w,
    const float* __restrict__ h0, const float* __restrict__ c0,
    const float* __restrict__ att_b, const int* __restrict__ input,
    const float* __restrict__ emb,
    float* __restrict__ scores, float* __restrict__ s_att,
    float* __restrict__ cat)
{
  __shared__ float red[4];
  int t = threadIdx.x;
  if (blockIdx.x < 8192) {
    int row = blockIdx.x * 4 + (t >> 6);
    int lane = t & 63;
    const float* p = enc + (size_t)row * Hd + lane * 16;
    const float* w = att_w + lane * 16;
    float s = 0.f;
    #pragma unroll
    for (int c = 0; c < 4; ++c) {
      float4 e = *(const float4*)(p + c * 4);
      float4 ww = *(const float4*)(w + c * 4);
      s += e.x * ww.x + e.y * ww.y + e.z * ww.z + e.w * ww.w;
    }
    s = wave_sum(s);
    if (lane == 0) scores[row] = s;     // s_att added in ctx softmax
  } else {
    int b = blockIdx.x - 8192;
    int idx = input[b];
    for (int j = t; j < Hd; j += 256)
      cat[b * 2 * Hd + Hd + j] = emb[(size_t)idx * Hd + j];
    size_t base = (size_t)(Bsz + b) * Hd;  // layer L-1 = 1
    float s = 0.f;
    for (int j = t; j < Hd; j += 256)
      s += h0[base + j] * c0[base + j] * att_w[Hd + j];
    s = wave_sum(s);
    if ((t & 63) == 0) red[t >> 6] = s;
    __syncthreads();
    if (t == 0) s_att[b] = red[0] + red[1] + red[2] + red[3] + att_b[0];
  }
}

// ---- ctx partials with in-block softmax: block = (b, chunk of 64 w-rows) ----
__global__ __launch_bounds__(256) void k_ctx_part(
    const float* __restrict__ scores, const float* __restrict__ s_att,
    const float* __restrict__ enc, float* __restrict__ part)  // part[b][8][Hd]
{
  int b = blockIdx.x >> 3, ch = blockIdx.x & 7;
  int t = threadIdx.x;
  float sa = s_att[b];
  const float* sr = scores + b * Wln;
  // shifted softmax over 512 positions: full[0]=0, full[w]=sr[w-1]+sa
  int w0 = t * 2, w1 = t * 2 + 1;
  float v0 = (w0 == 0) ? 0.f : sr[w0 - 1] + sa;
  float v1 = sr[w1 - 1] + sa;
  __shared__ float redm[4], reds[4];
  float m = fmaxf(v0, v1);
  m = wave_max(m);
  if ((t & 63) == 0) redm[t >> 6] = m;
  __syncthreads();
  float M = fmaxf(fmaxf(redm[0], redm[1]), fmaxf(redm[2], redm[3]));
  float e = expf(v0 - M) + expf(v1 - M);
  e = wave_sum(e);
  if ((t & 63) == 0) reds[t >> 6] = e;
  __syncthreads();
  float S = reds[0] + reds[1] + reds[2] + reds[3];
  __shared__ float w[64];
  if (t < 64) {
    int wg = ch * 64 + t;
    float v = (wg == 0) ? 0.f : sr[wg - 1] + sa;
    w[t] = expf(v - M) / S;
  }
  __syncthreads();
  int h4 = t * 4;
  const float* p = enc + (size_t)b * Wln * Hd + (size_t)ch * 64 * Hd + h4;
  float a0 = 0, a1 = 0, a2 = 0, a3 = 0;
  #pragma unroll 4
  for (int i = 0; i < 64; ++i) {
    float4 ev = *(const float4*)(p + (size_t)i * Hd);
    float wi = w[i];
    a0 += wi * ev.x; a1 += wi * ev.y; a2 += wi * ev.z; a3 += wi * ev.w;
  }
  float* o = part + ((size_t)b * 8 + ch) * Hd + h4;
  o[0] = a0; o[1] = a1; o[2] = a2; o[3] = a3;
}

__global__ __launch_bounds__(256) void k_ctx_red(
    const float* __restrict__ part, float* __restrict__ cat)
{
  int idx = blockIdx.x * 256 + threadIdx.x;  // 65536 = b*1024 + h
  int b = idx >> 10, h = idx & 1023;
  float s = 0.f;
  #pragma unroll
  for (int c = 0; c < 8; ++c) s += part[((size_t)b * 8 + c) * Hd + h];
  cat[b * 2 * Hd + h] = s;
}

// ---- GEMM v6: C(64 x N) = A(64 x 1024) * B(N x 1024)^T + bias ----
// A staged once per block in LDS (bf16, XOR-swizzled). 8 waves; NS n-subtiles
// of 16 cols; KS=8/NS K-split with LDS-reuse reduction. Dual problem sets.
// KEY (r9): each wave PRELOADS ITS FULL B K-SLICE into registers before the
// staging barrier -> ~12 KB/CU of loads in flight (1 blk/CU: VGPR is free).
template<int NS>
__global__ __launch_bounds__(512, 2) void gemm_v6(
    const float* __restrict__ A1, const float* __restrict__ A1b, int sA1,
    const float* __restrict__ B1, int sB1, const float* __restrict__ bias1,
    float* __restrict__ out1,
    const float* __restrict__ A2, const float* __restrict__ A2b, int sA2,
    const float* __restrict__ B2, int sB2, const float* __restrict__ bias2,
    float* __restrict__ out2,
    int N, int nblk1)
{
  constexpr int KS  = 8 / NS;       // K-split ways
  constexpr int KSL = 1024 / KS;    // k-slice per wave
  constexpr int NCH = KSL / 32;     // 32-k chunks per slice: 4/8/16
  const int tid = threadIdx.x;

  const float *A, *Ab, *B, *bias; float* out; int sA, sB, bid;
  if ((int)blockIdx.x < nblk1) {
    A = A1; Ab = A1b; sA = sA1; B = B1; sB = sB1; bias = bias1; out = out1;
    bid = blockIdx.x;
  } else {
    A = A2; Ab = A2b; sA = sA2; B = B2; sB = sB2; bias = bias2; out = out2;
    bid = blockIdx.x - nblk1;
  }

  __shared__ __align__(16) char pool[131072];   // 64 x 1024 bf16, swizzled

  const int w = tid >> 6, lane = tid & 63;
  const int r = lane & 15, q = lane >> 4;
  const int nsub = w % NS, kh = w / NS;
  const int n0 = bid * (NS * 16);

  // ---- issue full B K-slice preload (straight-line, before barrier) ----
  const float* bp = B + (size_t)(n0 + nsub * 16 + r) * sB + kh * KSL + q * 8;
  float4 breg[NCH][2];
  #pragma unroll
  for (int kk = 0; kk < NCH; ++kk) {
    breg[kk][0] = *(const float4*)(bp + kk * 32);
    breg[kk][1] = *(const float4*)(bp + kk * 32 + 4);
  }

  // ---- stage A (optionally A+Ab) -> LDS bf16 ----
  #pragma unroll
  for (int it = 0; it < 16; ++it) {
    int idx = it * 512 + tid;
    int row = idx >> 7, ch = idx & 127;       // 128 chunks of 8 f32 per row
    const float* src = A + (size_t)row * sA + ch * 8;
    float4 x0 = *(const float4*)src;
    float4 x1 = *(const float4*)(src + 4);
    if (Ab) {
      const float* s2 = Ab + (size_t)row * sA + ch * 8;
      float4 y0 = *(const float4*)s2;
      float4 y1 = *(const float4*)(s2 + 4);
      x0.x += y0.x; x0.y += y0.y; x0.z += y0.z; x0.w += y0.w;
      x1.x += y1.x; x1.y += y1.y; x1.z += y1.z; x1.w += y1.w;
    }
    *(v8s*)(pool + row * 2048 + ((ch * 16) ^ ((row & 7) << 4))) = cvt_frag(x0, x1);
  }
  __syncthreads();

  f32x4 acc[4] = {{0,0,0,0},{0,0,0,0},{0,0,0,0},{0,0,0,0}};
  const int swz = (r & 7) << 4;

  #pragma unroll
  for (int kk = 0; kk < NCH; ++kk) {
    v8s bf = cvt_frag(breg[kk][0], breg[kk][1]);
    int cb = ((kh * KSL + kk * 32 + q * 8) * 2) ^ swz;   // col byte, swizzled
    #pragma unroll
    for (int m = 0; m < 4; ++m) {
      v8s af = *(const v8s*)(pool + (m * 16 + r) * 2048 + cb);
      acc[m] = __builtin_amdgcn_mfma_f32_16x16x32_bf16(af, bf, acc[m], 0, 0, 0);
    }
  }

  __syncthreads();   // all A-reads done; reuse pool as reduction buffer
  float (*red)[64][17] = (float(*)[64][17])pool;
  #pragma unroll
  for (int m = 0; m < 4; ++m)
    #pragma unroll
    for (int rr = 0; rr < 4; ++rr)
      red[w][lane][m * 4 + rr] = acc[m][rr];
  __syncthreads();

  constexpr int COLS = NS * 16;
  #pragma unroll
  for (int it = 0; it < NS * 2; ++it) {
    int e = it * 512 + tid;                  // e in [0, 64*COLS)
    int cc = e % COLS, rowi = e / COLS;
    int ns2 = cc >> 4, lo = cc & 15;
    int idx = ((rowi >> 4) << 2) + (rowi & 3);
    int le  = (((rowi >> 2) & 3) << 4) + lo;
    float s = 0.f;
    #pragma unroll
    for (int j = 0; j < KS; ++j) s += red[ns2 + j * NS][le][idx];
    float bb = bias ? bias[n0 + cc] : 0.f;
    out[(size_t)rowi * N + n0 + cc] = s + bb;
  }
}

// ---- LSTM elementwise: g = g1 + g2; h,c straight to final f32 slots ----
__global__ __launch_bounds__(256) void k_lstm(
    const float* __restrict__ g1, const float* __restrict__ g2,
    const float* __restrict__ c0,
    float* __restrict__ out_h, float* __restrict__ out_c)
{
  int b = blockIdx.x >> 2;
  int j = ((blockIdx.x & 3) << 8) + threadIdx.x;
  const float* ga = g1 + (size_t)b * 4 * Hd;
  const float* gb = g2 + (size_t)b * 4 * Hd;
  float gi = ga[j] + gb[j];
  float gf = ga[Hd + j] + gb[Hd + j];
  float gg = ga[2 * Hd + j] + gb[2 * Hd + j];
  float go = ga[3 * Hd + j] + gb[3 * Hd + j];
  float c = sigm(gf) * c0[(size_t)b * Hd + j] + sigm(gi) * tanhf(gg);
  float h = sigm(go) * tanhf(c);
  out_h[b * Hd + j] = h;
  out_c[b * Hd + j] = c;
}

// ---- in-place log-softmax over V per batch row: 3-pass, float4 ----
__global__ __launch_bounds__(1024) void k_logsoftmax(float* __restrict__ lg)
{
  int b = blockIdx.x, t = threadIdx.x;
  float* row = lg + (size_t)b * Vc;
  __shared__ float red[16];
  float m = -1e30f;
  for (int w = t * 4; w < Vc; w += 4096) {
    float4 v = *(const float4*)(row + w);
    m = fmaxf(m, fmaxf(fmaxf(v.x, v.y), fmaxf(v.z, v.w)));
  }
  m = wave_max(m);
  if ((t & 63) == 0) red[t >> 6] = m;
  __syncthreads();
  float M = red[0];
  #pragma unroll
  for (int i = 1; i < 16; ++i) M = fmaxf(M, red[i]);
  __syncthreads();
  float s = 0.f;
  for (int w = t * 4; w < Vc; w += 4096) {
    float4 v = *(const float4*)(row + w);
    s += expf(v.x - M) + expf(v.y - M) + expf(v.z - M) + expf(v.w - M);
  }
  s = wave_sum(s);
  if ((t & 63) == 0) red[t >> 6] = s;
  __syncthreads();
  float S = red[0];
  #pragma unroll
  for (int i = 1; i < 16; ++i) S += red[i];
  float lse = M + logf(S);
  for (int w = t * 4; w < Vc; w += 4096) {
    float4 v = *(const float4*)(row + w);
    v.x -= lse; v.y -= lse; v.z -= lse; v.w -= lse;
    *(float4*)(row + w) = v;
  }
}

extern "C" void kernel_launch(void* const* d_in, const int* in_sizes, int n_in,
                              void* d_out, int out_size, void* d_ws, size_t ws_size,
                              hipStream_t stream)
{
  const int*   input = (const int*)d_in[0];
  const float* h0    = (const float*)d_in[1];
  const float* c0    = (const float*)d_in[2];
  const float* enc   = (const float*)d_in[3];
  const float* emb   = (const float*)d_in[4];
  const float* W_ih0 = (const float*)d_in[5];
  const float* W_hh0 = (const float*)d_in[6];
  const float* b_ih0 = (const float*)d_in[7];
  const float* b_hh0 = (const float*)d_in[8];
  const float* W_ih1 = (const float*)d_in[9];
  const float* W_hh1 = (const float*)d_in[10];
  const float* b_ih1 = (const float*)d_in[11];
  const float* b_hh1 = (const float*)d_in[12];
  const float* att_w = (const float*)d_in[13];
  const float* att_b = (const float*)d_in[14];
  const float* inW   = (const float*)d_in[15];
  const float* inb   = (const float*)d_in[16];
  const float* outW  = (const float*)d_in[17];
  const float* outb  = (const float*)d_in[18];
  float* out = (float*)d_out;

  // Scratch inside d_out's f32 logp region (8,192,000 B); all dead before
  // the logits GEMM overwrites it (logits reads h2/outW/outb only).
  char* sc = (char*)d_out;
  float* g1     = (float*)(sc + 0);          // 64x4096 f32 = 1 MB
  float* g2     = (float*)(sc + 1048576);    // 64x4096 f32 = 1 MB
  float* ctxp   = (float*)(sc + 2097152);    // 64x8x1024 f32 = 2 MB
  float* cat    = (float*)(sc + 4194304);    // 64x2048 f32: [ctx | emb]
  float* x1     = (float*)(sc + 4718592);    // 64x1024 f32
  float* x2     = (float*)(sc + 4980736);    // 64x1024 f32
  float* scores = (float*)(sc + 5242880);    // 64x512 f32
  float* s_att  = (float*)(sc + 5505024);    // 64 f32

  float* out_h = out + (size_t)Bsz * Vc;     // [2,B,H] f32
  float* out_c = out_h + 2 * Bsz * Hd;       // [2,B,H] f32
  float* h1 = out_h;                         // layer 0 slot
  float* h2 = out_h + Bsz * Hd;              // layer 1 slot

  k_scores_satt<<<8256, 256, 0, stream>>>(enc, att_w, h0, c0, att_b, input, emb,
                                          scores, s_att, cat);
  k_ctx_part<<<Bsz * 8, 256, 0, stream>>>(scores, s_att, enc, ctxp);
  k_ctx_red<<<Bsz * Hd / 256, 256, 0, stream>>>(ctxp, cat);

  // input proj: x = [ctx|emb] @ inW^T + inb, K-halves -> x1 + x2
  gemm_v6<1><<<128, 512, 0, stream>>>(
      cat,      nullptr, 2 * Hd, inW,      2 * Hd, inb,     x1,
      cat + Hd, nullptr, 2 * Hd, inW + Hd, 2 * Hd, nullptr, x2,
      Hd, 64);

  // layer 0 gates: g1 = (x1+x2)@W_ih0^T + b_ih0 ; g2 = h0@W_hh0^T + b_hh0
  gemm_v6<2><<<256, 512, 0, stream>>>(
      x1, x2,      Hd, W_ih0, Hd, b_ih0, g1,
      h0, nullptr, Hd, W_hh0, Hd, b_hh0, g2,
      4 * Hd, 128);
  k_lstm<<<Bsz * 4, 256, 0, stream>>>(g1, g2, c0, h1, out_c);

  // layer 1 gates
  gemm_v6<2><<<256, 512, 0, stream>>>(
      h1,                     nullptr, Hd, W_ih1, Hd, b_ih1, g1,
      h0 + (size_t)Bsz * Hd,  nullptr, Hd, W_hh1, Hd, b_hh1, g2,
      4 * Hd, 128);
  k_lstm<<<Bsz * 4, 256, 0, stream>>>(g1, g2, c0 + (size_t)Bsz * Hd, h2, out_c + Bsz * Hd);

  // logits
  gemm_v6<4><<<500, 512, 0, stream>>>(
      h2,      nullptr, Hd, outW,    Hd, outb,    out,
      nullptr, nullptr, 0,  nullptr, 0,  nullptr, nullptr,
      Vc, 500);
  k_logsoftmax<<<Bsz, 1024, 0, stream>>>(out);
}